// Round 5
// baseline (4391.553 us; speedup 1.0000x reference)
//
#include <hip/hip_runtime.h>

typedef _Float16 h8 __attribute__((ext_vector_type(8)));
typedef _Float16 h2 __attribute__((ext_vector_type(2)));
typedef float f4 __attribute__((ext_vector_type(4)));

#define N_NODES 100000
#define NPAD    100096   // 1564*64
#define N_EDGES 1600000
#define T_P  18
#define U    256
#define KP   288         // padded K: 8 AXt + 256 H + 24 zero
#define LDW  296         // LDS row stride in halfs (148 words = 20 mod 32 -> 2-way alias only, free)
#define NB_SCAN 391      // ceil(N_NODES/256)

// ---------------- degree / norm / CSR ----------------
__global__ void k_init_deg(float* deg){
    int i = blockIdx.x*256 + threadIdx.x;
    if (i < N_NODES) deg[i] = 1.0f;
}
__global__ void k_deg(const int* __restrict__ ei, const float* __restrict__ w, float* deg){
    int e = blockIdx.x*256 + threadIdx.x;
    if (e < N_EDGES) atomicAdd(&deg[ei[N_EDGES + e]], w[e]);
}
__global__ void k_dinv(const float* deg, float* dinv){
    int i = blockIdx.x*256 + threadIdx.x;
    if (i < N_NODES) dinv[i] = rsqrtf(deg[i]);
}
__global__ void k_count(const int* __restrict__ ei, int* cnt){
    int e = blockIdx.x*256 + threadIdx.x;
    if (e < N_EDGES) atomicAdd(&cnt[ei[N_EDGES + e]], 1);
}
// parallel scan: per-256-chunk sums -> scan of partials -> emit offsets
__global__ void k_partial(const int* __restrict__ cnt, int* part){
    __shared__ int red[256];
    int b = blockIdx.x, i = b*256 + threadIdx.x;
    red[threadIdx.x] = (i < N_NODES) ? cnt[i] : 0;
    __syncthreads();
    for (int d = 128; d > 0; d >>= 1){
        if (threadIdx.x < d) red[threadIdx.x] += red[threadIdx.x + d];
        __syncthreads();
    }
    if (threadIdx.x == 0) part[b] = red[0];
}
__global__ void k_scan_part(const int* __restrict__ part, int* pbase){
    __shared__ int s[512];
    int tid = threadIdx.x;
    int v = (tid < NB_SCAN) ? part[tid] : 0;
    s[tid] = v; __syncthreads();
    for (int d = 1; d < 512; d <<= 1){
        int t2 = (tid >= d) ? s[tid - d] : 0;
        __syncthreads();
        s[tid] += t2;
        __syncthreads();
    }
    if (tid < NB_SCAN) pbase[tid] = s[tid] - v;   // exclusive
}
__global__ void k_emit(const int* __restrict__ cnt, const int* __restrict__ pbase,
                       int* rowp, int* ccur){
    __shared__ int s[256];
    int b = blockIdx.x, tid = threadIdx.x, i = b*256 + tid;
    int v = (i < N_NODES) ? cnt[i] : 0;
    s[tid] = v; __syncthreads();
    for (int d = 1; d < 256; d <<= 1){
        int t2 = (tid >= d) ? s[tid - d] : 0;
        __syncthreads();
        s[tid] += t2;
        __syncthreads();
    }
    int excl = s[tid] - v + pbase[b];
    if (i < N_NODES){
        rowp[i] = excl; ccur[i] = excl;
        if (i == N_NODES - 1) rowp[N_NODES] = excl + v;
    }
}
__global__ void k_scatter(const int* __restrict__ ei, const float* __restrict__ w,
                          const float* __restrict__ dinv, int* ccur,
                          int* __restrict__ csrc, float* __restrict__ cnrm){
    int e = blockIdx.x*256 + threadIdx.x;
    if (e >= N_EDGES) return;
    int s = ei[e], d = ei[N_EDGES + e];
    int pos = atomicAdd(&ccur[d], 1);
    csrc[pos] = s;
    cnrm[pos] = dinv[s] * w[e] * dinv[d];
}
// one thread per (node, feature): 18 time-accumulators, fp16 out
__global__ void k_gather_nf(const float* __restrict__ x, const float* __restrict__ dinv,
                            const int* __restrict__ rowp, const int* __restrict__ csrc,
                            const float* __restrict__ cnrm, _Float16* __restrict__ AXh){
    int idx = blockIdx.x*256 + threadIdx.x;
    if (idx >= N_NODES*8) return;
    int n = idx >> 3, f = idx & 7;
    float dv = dinv[n];
    float w0 = dv * dv;
    const float* xb = x + (size_t)n*144 + f*18;
    float s[T_P];
    #pragma unroll
    for (int t = 0; t < T_P; t++) s[t] = w0 * xb[t];
    int p1 = rowp[n+1];
    for (int p = rowp[n]; p < p1; p++){
        float w = cnrm[p];
        const float* xs = x + (size_t)csrc[p]*144 + f*18;
        #pragma unroll
        for (int t = 0; t < T_P; t++) s[t] += w * xs[t];
    }
    #pragma unroll
    for (int t = 0; t < T_P; t++)
        AXh[((size_t)t*NPAD + n)*8 + f] = (_Float16)s[t];
}

// ---------------- weight prep ----------------
__global__ void k_probs(const float* att, float* probs){
    if (threadIdx.x == 0 && blockIdx.x == 0){
        float mx = -1e30f;
        for (int t = 0; t < T_P; t++) mx = fmaxf(mx, att[t]);
        float e[T_P], s = 0.f;
        for (int t = 0; t < T_P; t++){ e[t] = __expf(att[t] - mx); s += e[t]; }
        for (int t = 0; t < T_P; t++) probs[t] = e[t] / s;
    }
}
__global__ void k_wprime(const float* Wz, const float* bz, const float* Wlz, const float* blz,
                         const float* Wr, const float* br, const float* Wlr, const float* blr,
                         const float* Wh, const float* bh, const float* Wlh, const float* blh,
                         float* wprime, float* biasg){
    int idx = blockIdx.x*256 + threadIdx.x;
    if (idx >= 3*9*256) return;
    int g = idx / (9*256); int rem = idx - g*9*256;
    int row = rem / 256;   int u = rem - row*256;
    const float* W  = g==0 ? Wz  : (g==1 ? Wr  : Wh);
    const float* Wl = g==0 ? Wlz : (g==1 ? Wlr : Wlh);
    const float* bb = g==0 ? bz  : (g==1 ? br  : bh);
    const float* bl = g==0 ? blz : (g==1 ? blr : blh);
    float s = 0.f;
    if (row < 8){
        for (int c = 0; c < U; c++) s += W[row*U + c] * Wl[c*U + u];
        wprime[(g*8 + row)*U + u] = s;
    } else {
        for (int c = 0; c < U; c++) s += bb[c] * Wl[c*U + u];
        biasg[g*U + u] = s + bl[u];
    }
}
// B1t [512][288] (Z|R), B2t [256][288] (H~), n-major fp16, K-padded with 0
__global__ void k_fill_gates(const float* __restrict__ wprime, const float* __restrict__ Wlz,
                             const float* __restrict__ Wlr, const float* __restrict__ Wlh,
                             _Float16* __restrict__ B1t, _Float16* __restrict__ B2t){
    int idx = blockIdx.x*256 + threadIdx.x;
    if (idx >= 768*KP) return;
    int n = idx / KP, k = idx - n*KP;
    int g = (n < 256) ? 0 : ((n < 512) ? 1 : 2);
    int u = n & 255;
    const float* Wl = g==0 ? Wlz : (g==1 ? Wlr : Wlh);
    float v;
    if (k < 8)        v = wprime[(g*8 + k)*U + u];
    else if (k < 264) v = Wl[(256 + (k - 8))*U + u];
    else              v = 0.f;
    if (n < 512) B1t[(size_t)n*KP + k] = (_Float16)v;
    else         B2t[(size_t)(n - 512)*KP + k] = (_Float16)v;
}
// MLP weights in same padded layout: rows k<8 and k>=264 are zero, k in [8,264) = W[k-8][n]
__global__ void k_fill_mlp(const float* __restrict__ W1, const float* __restrict__ W2,
                           const float* __restrict__ W3, const float* __restrict__ Wo,
                           _Float16* W1t, _Float16* W2t, _Float16* W3t, _Float16* WoT){
    int idx = blockIdx.x*256 + threadIdx.x;
    if (idx >= 3*U*KP + 64*KP) return;
    if (idx < 3*U*KP){
        int l = idx / (U*KP); int rem = idx - l*U*KP;
        int n = rem / KP, k = rem - n*KP;
        const float* W = l==0 ? W1 : (l==1 ? W2 : W3);
        _Float16*   Wt = l==0 ? W1t : (l==1 ? W2t : W3t);
        Wt[(size_t)n*KP + k] = (k >= 8 && k < 264) ? (_Float16)W[(size_t)(k-8)*U + n] : (_Float16)0.f;
    } else {
        int rem = idx - 3*U*KP;
        int n = rem / KP, k = rem - n*KP;
        WoT[(size_t)n*KP + k] = (n < T_P && k >= 8 && k < 264) ? (_Float16)Wo[(size_t)(k-8)*T_P + n] : (_Float16)0.f;
    }
}

// ---------------- fused recurrence + MLP ----------------
__device__ __forceinline__ void gemm_pass(const _Float16* sbuf, const _Float16* __restrict__ Bg,
                                          int brow0, int lr, int lq, int wc, f4* g){
    for (int kt = 0; kt < 9; kt++){
        h8 af[4], bf[4];
        #pragma unroll
        for (int i = 0; i < 4; i++)
            af[i] = *(const h8*)(sbuf + (i*16 + lr)*LDW + kt*32 + lq*8);
        #pragma unroll
        for (int j = 0; j < 4; j++)
            bf[j] = *(const h8*)(Bg + (size_t)(brow0 + wc + j*16 + lr)*KP + kt*32 + lq*8);
        #pragma unroll
        for (int i = 0; i < 4; i++)
            #pragma unroll
            for (int j = 0; j < 4; j++)
                g[i*4 + j] = __builtin_amdgcn_mfma_f32_16x16x32_f16(af[i], bf[j], g[i*4 + j], 0, 0, 0);
    }
}

// Round-4 post-mortem: peak live state (Z+Hh+acc = 96 VGPR) > 128-cap -> ~70 spilled
// regs -> 2.6 GB scratch writes (WRITE_SIZE) + L2 thrash (7.4 GB FETCH).
// Fix: gate reorder R -> H~ -> Z so only ht[32] (+acc[32]) is live across a GEMM.
// H*R goes to a second LDS buffer instead of registers.
__global__ __launch_bounds__(256, 2)
void k_fused(const _Float16* __restrict__ AXh,
             const _Float16* __restrict__ B1t, const _Float16* __restrict__ B2t,
             const float* __restrict__ biasg,
             const _Float16* __restrict__ W1t, const _Float16* __restrict__ W2t,
             const _Float16* __restrict__ W3t, const _Float16* __restrict__ WoT,
             const float* __restrict__ b1, const float* __restrict__ b2,
             const float* __restrict__ b3, const float* __restrict__ bo,
             const float* __restrict__ probs, float* __restrict__ dout){
    __shared__ __align__(16) _Float16 sA[64*LDW];   // [AXt | H    | pad]
    __shared__ __align__(16) _Float16 sB[64*LDW];   // [AXt | H*R  | pad]
    const int tid  = threadIdx.x;
    const int wave = tid >> 6, lane = tid & 63;
    const int lr = lane & 15, lq = lane >> 4;
    const int wc = wave * 64;
    const int n0 = blockIdx.x * 64;

    {   // zero both buffers (H cols start 0, pad cols stay 0)
        uint* w0 = (uint*)sA; uint* w1 = (uint*)sB;
        for (int i = tid; i < 64*LDW/2; i += 256){ w0[i] = 0u; w1[i] = 0u; }
    }
    __syncthreads();
    if (tid < 64)
        *(uint4*)(&sA[tid*LDW]) = *(const uint4*)(AXh + ((size_t)0*NPAD + n0 + tid)*8);
    else if (tid < 128)
        *(uint4*)(&sB[(tid-64)*LDW]) = *(const uint4*)(AXh + ((size_t)0*NPAD + n0 + (tid-64))*8);

    // hoist biases (constant across t): 12 VGPRs
    float bz_r[4], br_r[4], bh_r[4];
    #pragma unroll
    for (int j = 0; j < 4; j++){
        int col = wc + j*16 + lr;
        bz_r[j] = biasg[col];
        br_r[j] = biasg[256 + col];
        bh_r[j] = biasg[512 + col];
    }

    h2 acc[32], ht[32];
    h2 z2 = {(_Float16)0.f, (_Float16)0.f};
    #pragma unroll
    for (int k = 0; k < 32; k++) acc[k] = z2;

    f4 g[16];
    const f4 fz = {0.f, 0.f, 0.f, 0.f};
    __syncthreads();

    for (int t = 0; t < T_P; t++){
        const float pt = probs[t];
        const int last = (t == T_P - 1);
        // ---- GEMM-R (reads sA) ----
        #pragma unroll
        for (int k = 0; k < 16; k++) g[k] = fz;
        gemm_pass(sA, B1t, 256, lr, lq, wc, g);
        // epi-R: sB.H = sA.H * sigmoid(.)   (writes sB only; sA reads by others OK)
        #pragma unroll
        for (int i = 0; i < 4; i++)
            #pragma unroll
            for (int j = 0; j < 4; j++)
                #pragma unroll
                for (int r = 0; r < 4; r++){
                    int row = i*16 + lq*4 + r;
                    int col = wc + j*16 + lr;
                    float rr = 1.f / (1.f + __expf(-(g[i*4 + j][r] + br_r[j])));
                    sB[row*LDW + 8 + col] = (_Float16)((float)sA[row*LDW + 8 + col] * rr);
                }
        __syncthreads();                       // sB (H*R) complete
        // ---- GEMM-H~ (reads sB) ----
        #pragma unroll
        for (int k = 0; k < 16; k++) g[k] = fz;
        gemm_pass(sB, B2t, 0, lr, lq, wc, g);
        #pragma unroll
        for (int i = 0; i < 4; i++)
            #pragma unroll
            for (int j = 0; j < 4; j++)
                #pragma unroll
                for (int r = 0; r < 4; r++){
                    int v = (i*4 + j)*4 + r;
                    float val = g[i*4 + j][r] + bh_r[j];
                    float e2 = __expf(2.f*val);
                    ht[v>>1][v&1] = (_Float16)(1.f - 2.f/(e2 + 1.f));
                }
        // ---- GEMM-Z (reads sA; no sync needed, reads only) ----
        #pragma unroll
        for (int k = 0; k < 16; k++) g[k] = fz;
        gemm_pass(sA, B1t, 0, lr, lq, wc, g);
        __syncthreads();                       // all GEMM-Z reads of sA done
        // epi-Z: GRU update in place + attention accumulate (+ final relu fuse)
        #pragma unroll
        for (int i = 0; i < 4; i++)
            #pragma unroll
            for (int j = 0; j < 4; j++)
                #pragma unroll
                for (int r = 0; r < 4; r++){
                    int v = (i*4 + j)*4 + r;
                    int row = i*16 + lq*4 + r;
                    int col = wc + j*16 + lr;
                    float z  = 1.f / (1.f + __expf(-(g[i*4 + j][r] + bz_r[j])));
                    float h  = (float)sA[row*LDW + 8 + col];
                    float hn = z*h + (1.f - z)*(float)ht[v>>1][v&1];
                    float a  = (float)acc[v>>1][v&1] + pt*hn;
                    acc[v>>1][v&1] = (_Float16)a;
                    sA[row*LDW + 8 + col] = (_Float16)(last ? fmaxf(a, 0.f) : hn);
                }
        if (!last){
            if (tid < 64)
                *(uint4*)(&sA[tid*LDW]) = *(const uint4*)(AXh + ((size_t)(t+1)*NPAD + n0 + tid)*8);
            else if (tid < 128)
                *(uint4*)(&sB[(tid-64)*LDW]) = *(const uint4*)(AXh + ((size_t)(t+1)*NPAD + n0 + (tid-64))*8);
        }
        __syncthreads();                       // H' (or relu(acc)), AXt+1 visible
    }

    // ---- MLP in place on sA; stale AXt cols nulled by zero rows in W*t ----
    const _Float16* Ws[3] = {W1t, W2t, W3t};
    const float*    bs[3] = {b1, b2, b3};
    for (int l = 0; l < 3; l++){
        #pragma unroll
        for (int k = 0; k < 16; k++) g[k] = fz;
        gemm_pass(sA, Ws[l], 0, lr, lq, wc, g);
        __syncthreads();                       // all reads done before in-place write
        #pragma unroll
        for (int i = 0; i < 4; i++)
            #pragma unroll
            for (int j = 0; j < 4; j++)
                #pragma unroll
                for (int r = 0; r < 4; r++){
                    int row = i*16 + lq*4 + r;
                    int col = wc + j*16 + lr;
                    sA[row*LDW + 8 + col] = (_Float16)fmaxf(g[i*4 + j][r] + bs[l][col], 0.f);
                }
        __syncthreads();
    }
    // ---- head: 64x18, wave 0 only ----
    if (wave == 0){
        #pragma unroll
        for (int k = 0; k < 16; k++) g[k] = fz;
        gemm_pass(sA, WoT, 0, lr, lq, 0, g);
        #pragma unroll
        for (int i = 0; i < 4; i++)
            #pragma unroll
            for (int j = 0; j < 4; j++)
                #pragma unroll
                for (int r = 0; r < 4; r++){
                    int row = i*16 + lq*4 + r;
                    int col = j*16 + lr;
                    int gm = n0 + row;
                    if (col < T_P && gm < N_NODES)
                        dout[(size_t)gm*T_P + col] = g[i*4 + j][r] + bo[col];
                }
    }
}

extern "C" void kernel_launch(void* const* d_in, const int* in_sizes, int n_in,
                              void* d_out, int out_size, void* d_ws, size_t ws_size,
                              hipStream_t stream){
    const float* x   = (const float*)d_in[0];
    const int*   ei  = (const int*)  d_in[1];
    const float* ew  = (const float*)d_in[2];
    const float* Wz  = (const float*)d_in[3];  const float* bz  = (const float*)d_in[4];
    const float* Wlz = (const float*)d_in[5];  const float* blz = (const float*)d_in[6];
    const float* Wr  = (const float*)d_in[7];  const float* br  = (const float*)d_in[8];
    const float* Wlr = (const float*)d_in[9];  const float* blr = (const float*)d_in[10];
    const float* Wh  = (const float*)d_in[11]; const float* bh  = (const float*)d_in[12];
    const float* Wlh = (const float*)d_in[13]; const float* blh = (const float*)d_in[14];
    const float* att = (const float*)d_in[15];
    const float* W1  = (const float*)d_in[16]; const float* b1  = (const float*)d_in[17];
    const float* W2  = (const float*)d_in[18]; const float* b2  = (const float*)d_in[19];
    const float* W3  = (const float*)d_in[20]; const float* b3  = (const float*)d_in[21];
    const float* Wo  = (const float*)d_in[22]; const float* bo  = (const float*)d_in[23];
    float* dout = (float*)d_out;

    char* ws = (char*)d_ws; size_t off = 0;
    auto alloc = [&](size_t bytes)->char*{ char* p = ws + off; off += (bytes + 255) & ~(size_t)255; return p; };
    _Float16* AXh   = (_Float16*)alloc((size_t)T_P*NPAD*8*2);   // 28.8M
    float*    deg   = (float*)alloc((size_t)N_NODES*4);
    float*    dinv  = (float*)alloc((size_t)N_NODES*4);
    int*      cnt   = (int*)  alloc((size_t)N_NODES*4);
    int*      rowp  = (int*)  alloc(((size_t)N_NODES + 1)*4);
    int*      ccur  = (int*)  alloc((size_t)N_NODES*4);
    int*      csrc  = (int*)  alloc((size_t)N_EDGES*4);
    float*    cnrm  = (float*)alloc((size_t)N_EDGES*4);
    int*      part  = (int*)  alloc((size_t)NB_SCAN*4);
    int*      pbase = (int*)  alloc((size_t)NB_SCAN*4);
    float*    wprime= (float*)alloc((size_t)3*8*U*4);
    float*    biasg = (float*)alloc((size_t)3*U*4);
    _Float16* B1t   = (_Float16*)alloc((size_t)512*KP*2);
    _Float16* B2t   = (_Float16*)alloc((size_t)256*KP*2);
    _Float16* W1t   = (_Float16*)alloc((size_t)U*KP*2);
    _Float16* W2t   = (_Float16*)alloc((size_t)U*KP*2);
    _Float16* W3t   = (_Float16*)alloc((size_t)U*KP*2);
    _Float16* WoT   = (_Float16*)alloc((size_t)64*KP*2);
    float*    probs = (float*)alloc((size_t)T_P*4);

    hipMemsetAsync(AXh, 0, (size_t)T_P*NPAD*8*2, stream);   // pad-node rows stay zero
    hipMemsetAsync(cnt, 0, (size_t)N_NODES*4, stream);

    k_probs<<<1, 64, 0, stream>>>(att, probs);
    k_wprime<<<(3*9*256 + 255)/256, 256, 0, stream>>>(Wz,bz,Wlz,blz, Wr,br,Wlr,blr, Wh,bh,Wlh,blh, wprime, biasg);
    k_fill_gates<<<(768*KP + 255)/256, 256, 0, stream>>>(wprime, Wlz, Wlr, Wlh, B1t, B2t);
    k_fill_mlp<<<(3*U*KP + 64*KP + 255)/256, 256, 0, stream>>>(W1, W2, W3, Wo, W1t, W2t, W3t, WoT);

    k_init_deg<<<(N_NODES + 255)/256, 256, 0, stream>>>(deg);
    k_deg<<<(N_EDGES + 255)/256, 256, 0, stream>>>(ei, ew, deg);
    k_dinv<<<(N_NODES + 255)/256, 256, 0, stream>>>(deg, dinv);
    k_count<<<(N_EDGES + 255)/256, 256, 0, stream>>>(ei, cnt);
    k_partial<<<NB_SCAN, 256, 0, stream>>>(cnt, part);
    k_scan_part<<<1, 512, 0, stream>>>(part, pbase);
    k_emit<<<NB_SCAN, 256, 0, stream>>>(cnt, pbase, rowp, ccur);
    k_scatter<<<(N_EDGES + 255)/256, 256, 0, stream>>>(ei, ew, dinv, ccur, csrc, cnrm);
    k_gather_nf<<<(N_NODES*8 + 255)/256, 256, 0, stream>>>(x, dinv, rowp, csrc, cnrm, AXh);

    k_fused<<<NPAD/64, 256, 0, stream>>>(AXh, B1t, B2t, biasg, W1t, W2t, W3t, WoT,
                                         b1, b2, b3, bo, probs, dout);
}

// Round 6
// 3941.941 us; speedup vs baseline: 1.1141x; 1.1141x over previous
//
#include <hip/hip_runtime.h>

typedef _Float16 h8 __attribute__((ext_vector_type(8)));
typedef _Float16 h2 __attribute__((ext_vector_type(2)));
typedef float f4 __attribute__((ext_vector_type(4)));

#define N_NODES 100000
#define NPAD    100096   // 1564*64
#define N_EDGES 1600000
#define T_P  18
#define U    256
#define KP   288         // padded K: 8 AXt + 256 H + 24 zero
#define LDW  296         // LDS row stride in halfs (148 words = 20 mod 32 -> 2-way alias only, free)
#define NB_SCAN 391      // ceil(N_NODES/256)

// ---------------- degree / norm / CSR ----------------
__global__ void k_init_deg(float* deg){
    int i = blockIdx.x*256 + threadIdx.x;
    if (i < N_NODES) deg[i] = 1.0f;
}
__global__ void k_deg(const int* __restrict__ ei, const float* __restrict__ w, float* deg){
    int e = blockIdx.x*256 + threadIdx.x;
    if (e < N_EDGES) atomicAdd(&deg[ei[N_EDGES + e]], w[e]);
}
__global__ void k_dinv(const float* deg, float* dinv){
    int i = blockIdx.x*256 + threadIdx.x;
    if (i < N_NODES) dinv[i] = rsqrtf(deg[i]);
}
__global__ void k_count(const int* __restrict__ ei, int* cnt){
    int e = blockIdx.x*256 + threadIdx.x;
    if (e < N_EDGES) atomicAdd(&cnt[ei[N_EDGES + e]], 1);
}
// parallel scan: per-256-chunk sums -> scan of partials -> emit offsets
__global__ void k_partial(const int* __restrict__ cnt, int* part){
    __shared__ int red[256];
    int b = blockIdx.x, i = b*256 + threadIdx.x;
    red[threadIdx.x] = (i < N_NODES) ? cnt[i] : 0;
    __syncthreads();
    for (int d = 128; d > 0; d >>= 1){
        if (threadIdx.x < d) red[threadIdx.x] += red[threadIdx.x + d];
        __syncthreads();
    }
    if (threadIdx.x == 0) part[b] = red[0];
}
__global__ void k_scan_part(const int* __restrict__ part, int* pbase){
    __shared__ int s[512];
    int tid = threadIdx.x;
    int v = (tid < NB_SCAN) ? part[tid] : 0;
    s[tid] = v; __syncthreads();
    for (int d = 1; d < 512; d <<= 1){
        int t2 = (tid >= d) ? s[tid - d] : 0;
        __syncthreads();
        s[tid] += t2;
        __syncthreads();
    }
    if (tid < NB_SCAN) pbase[tid] = s[tid] - v;   // exclusive
}
__global__ void k_emit(const int* __restrict__ cnt, const int* __restrict__ pbase,
                       int* rowp, int* ccur){
    __shared__ int s[256];
    int b = blockIdx.x, tid = threadIdx.x, i = b*256 + tid;
    int v = (i < N_NODES) ? cnt[i] : 0;
    s[tid] = v; __syncthreads();
    for (int d = 1; d < 256; d <<= 1){
        int t2 = (tid >= d) ? s[tid - d] : 0;
        __syncthreads();
        s[tid] += t2;
        __syncthreads();
    }
    int excl = s[tid] - v + pbase[b];
    if (i < N_NODES){
        rowp[i] = excl; ccur[i] = excl;
        if (i == N_NODES - 1) rowp[N_NODES] = excl + v;
    }
}
__global__ void k_scatter(const int* __restrict__ ei, const float* __restrict__ w,
                          const float* __restrict__ dinv, int* ccur,
                          int* __restrict__ csrc, float* __restrict__ cnrm){
    int e = blockIdx.x*256 + threadIdx.x;
    if (e >= N_EDGES) return;
    int s = ei[e], d = ei[N_EDGES + e];
    int pos = atomicAdd(&ccur[d], 1);
    csrc[pos] = s;
    cnrm[pos] = dinv[s] * w[e] * dinv[d];
}
// one thread per (node, feature): 18 time-accumulators, fp16 out
__global__ void k_gather_nf(const float* __restrict__ x, const float* __restrict__ dinv,
                            const int* __restrict__ rowp, const int* __restrict__ csrc,
                            const float* __restrict__ cnrm, _Float16* __restrict__ AXh){
    int idx = blockIdx.x*256 + threadIdx.x;
    if (idx >= N_NODES*8) return;
    int n = idx >> 3, f = idx & 7;
    float dv = dinv[n];
    float w0 = dv * dv;
    const float* xb = x + (size_t)n*144 + f*18;
    float s[T_P];
    #pragma unroll
    for (int t = 0; t < T_P; t++) s[t] = w0 * xb[t];
    int p1 = rowp[n+1];
    for (int p = rowp[n]; p < p1; p++){
        float w = cnrm[p];
        const float* xs = x + (size_t)csrc[p]*144 + f*18;
        #pragma unroll
        for (int t = 0; t < T_P; t++) s[t] += w * xs[t];
    }
    #pragma unroll
    for (int t = 0; t < T_P; t++)
        AXh[((size_t)t*NPAD + n)*8 + f] = (_Float16)s[t];
}

// ---------------- weight prep ----------------
__global__ void k_probs(const float* att, float* probs){
    if (threadIdx.x == 0 && blockIdx.x == 0){
        float mx = -1e30f;
        for (int t = 0; t < T_P; t++) mx = fmaxf(mx, att[t]);
        float e[T_P], s = 0.f;
        for (int t = 0; t < T_P; t++){ e[t] = __expf(att[t] - mx); s += e[t]; }
        for (int t = 0; t < T_P; t++) probs[t] = e[t] / s;
    }
}
__global__ void k_wprime(const float* Wz, const float* bz, const float* Wlz, const float* blz,
                         const float* Wr, const float* br, const float* Wlr, const float* blr,
                         const float* Wh, const float* bh, const float* Wlh, const float* blh,
                         float* wprime, float* biasg){
    int idx = blockIdx.x*256 + threadIdx.x;
    if (idx >= 3*9*256) return;
    int g = idx / (9*256); int rem = idx - g*9*256;
    int row = rem / 256;   int u = rem - row*256;
    const float* W  = g==0 ? Wz  : (g==1 ? Wr  : Wh);
    const float* Wl = g==0 ? Wlz : (g==1 ? Wlr : Wlh);
    const float* bb = g==0 ? bz  : (g==1 ? br  : bh);
    const float* bl = g==0 ? blz : (g==1 ? blr : blh);
    float s = 0.f;
    if (row < 8){
        for (int c = 0; c < U; c++) s += W[row*U + c] * Wl[c*U + u];
        wprime[(g*8 + row)*U + u] = s;
    } else {
        for (int c = 0; c < U; c++) s += bb[c] * Wl[c*U + u];
        biasg[g*U + u] = s + bl[u];
    }
}
// B1t [512][288] (Z|R), B2t [256][288] (H~), n-major fp16, K-padded with 0
__global__ void k_fill_gates(const float* __restrict__ wprime, const float* __restrict__ Wlz,
                             const float* __restrict__ Wlr, const float* __restrict__ Wlh,
                             _Float16* __restrict__ B1t, _Float16* __restrict__ B2t){
    int idx = blockIdx.x*256 + threadIdx.x;
    if (idx >= 768*KP) return;
    int n = idx / KP, k = idx - n*KP;
    int g = (n < 256) ? 0 : ((n < 512) ? 1 : 2);
    int u = n & 255;
    const float* Wl = g==0 ? Wlz : (g==1 ? Wlr : Wlh);
    float v;
    if (k < 8)        v = wprime[(g*8 + k)*U + u];
    else if (k < 264) v = Wl[(256 + (k - 8))*U + u];
    else              v = 0.f;
    if (n < 512) B1t[(size_t)n*KP + k] = (_Float16)v;
    else         B2t[(size_t)(n - 512)*KP + k] = (_Float16)v;
}
// MLP weights in same padded layout: rows k<8 and k>=264 are zero, k in [8,264) = W[k-8][n]
__global__ void k_fill_mlp(const float* __restrict__ W1, const float* __restrict__ W2,
                           const float* __restrict__ W3, const float* __restrict__ Wo,
                           _Float16* W1t, _Float16* W2t, _Float16* W3t, _Float16* WoT){
    int idx = blockIdx.x*256 + threadIdx.x;
    if (idx >= 3*U*KP + 64*KP) return;
    if (idx < 3*U*KP){
        int l = idx / (U*KP); int rem = idx - l*U*KP;
        int n = rem / KP, k = rem - n*KP;
        const float* W = l==0 ? W1 : (l==1 ? W2 : W3);
        _Float16*   Wt = l==0 ? W1t : (l==1 ? W2t : W3t);
        Wt[(size_t)n*KP + k] = (k >= 8 && k < 264) ? (_Float16)W[(size_t)(k-8)*U + n] : (_Float16)0.f;
    } else {
        int rem = idx - 3*U*KP;
        int n = rem / KP, k = rem - n*KP;
        WoT[(size_t)n*KP + k] = (n < T_P && k >= 8 && k < 264) ? (_Float16)Wo[(size_t)(k-8)*T_P + n] : (_Float16)0.f;
    }
}

// ---------------- fused recurrence + MLP ----------------
__device__ __forceinline__ void gemm_pass(const _Float16* sbuf, const _Float16* __restrict__ Bg,
                                          int brow0, int lr, int lq, int wc, f4* g){
    for (int kt = 0; kt < 9; kt++){
        h8 af[4], bf[4];
        #pragma unroll
        for (int i = 0; i < 4; i++)
            af[i] = *(const h8*)(sbuf + (i*16 + lr)*LDW + kt*32 + lq*8);
        #pragma unroll
        for (int j = 0; j < 4; j++)
            bf[j] = *(const h8*)(Bg + (size_t)(brow0 + wc + j*16 + lr)*KP + kt*32 + lq*8);
        #pragma unroll
        for (int i = 0; i < 4; i++)
            #pragma unroll
            for (int j = 0; j < 4; j++)
                g[i*4 + j] = __builtin_amdgcn_mfma_f32_16x16x32_f16(af[i], bf[j], g[i*4 + j], 0, 0, 0);
    }
}

// Round-5 post-mortem: gfx950 unified VGPR/AGPR file — waves_per_eu(2,2) budget is
// 256 TOTAL regs/wave; kernel needs 128 arch + ~128 acc -> it was already at the cap
// and kept spilling (0.84 GB scratch writes -> L2 thrash -> 7 GB HBM fetch).
// Fix: waves_per_eu(1) (512-reg budget; occupancy is LDS-bound at 2 blocks/CU anyway)
// + move the ht[32] gate array into sB's H-columns (thread-owned slots).
__global__ __attribute__((amdgpu_waves_per_eu(1))) __launch_bounds__(256)
void k_fused(const _Float16* __restrict__ AXh,
             const _Float16* __restrict__ B1t, const _Float16* __restrict__ B2t,
             const float* __restrict__ biasg,
             const _Float16* __restrict__ W1t, const _Float16* __restrict__ W2t,
             const _Float16* __restrict__ W3t, const _Float16* __restrict__ WoT,
             const float* __restrict__ b1, const float* __restrict__ b2,
             const float* __restrict__ b3, const float* __restrict__ bo,
             const float* __restrict__ probs, float* __restrict__ dout){
    __shared__ __align__(16) _Float16 sA[64*LDW];   // [AXt | H        | pad]
    __shared__ __align__(16) _Float16 sB[64*LDW];   // [AXt | H*R / ht | pad]
    const int tid  = threadIdx.x;
    const int wave = tid >> 6, lane = tid & 63;
    const int lr = lane & 15, lq = lane >> 4;
    const int wc = wave * 64;
    const int n0 = blockIdx.x * 64;

    {   // zero both buffers (H cols start 0, pad cols stay 0)
        uint* w0 = (uint*)sA; uint* w1 = (uint*)sB;
        for (int i = tid; i < 64*LDW/2; i += 256){ w0[i] = 0u; w1[i] = 0u; }
    }
    __syncthreads();
    if (tid < 64)
        *(uint4*)(&sA[tid*LDW]) = *(const uint4*)(AXh + ((size_t)0*NPAD + n0 + tid)*8);
    else if (tid < 128)
        *(uint4*)(&sB[(tid-64)*LDW]) = *(const uint4*)(AXh + ((size_t)0*NPAD + n0 + (tid-64))*8);

    // hoist biases (constant across t): 12 VGPRs
    float bz_r[4], br_r[4], bh_r[4];
    #pragma unroll
    for (int j = 0; j < 4; j++){
        int col = wc + j*16 + lr;
        bz_r[j] = biasg[col];
        br_r[j] = biasg[256 + col];
        bh_r[j] = biasg[512 + col];
    }

    h2 acc[32];
    h2 z2 = {(_Float16)0.f, (_Float16)0.f};
    #pragma unroll
    for (int k = 0; k < 32; k++) acc[k] = z2;

    f4 g[16];
    const f4 fz = {0.f, 0.f, 0.f, 0.f};
    __syncthreads();

    for (int t = 0; t < T_P; t++){
        const float pt = probs[t];
        const int last = (t == T_P - 1);
        // ---- GEMM-R (reads sA) ----
        #pragma unroll
        for (int k = 0; k < 16; k++) g[k] = fz;
        gemm_pass(sA, B1t, 256, lr, lq, wc, g);
        // epi-R: sB.H = sA.H * sigmoid(.)  (sB free: last reader was prior epi-Z, same thread)
        #pragma unroll
        for (int i = 0; i < 4; i++)
            #pragma unroll
            for (int j = 0; j < 4; j++)
                #pragma unroll
                for (int r = 0; r < 4; r++){
                    int row = i*16 + lq*4 + r;
                    int col = wc + j*16 + lr;
                    float rr = 1.f / (1.f + __expf(-(g[i*4 + j][r] + br_r[j])));
                    sB[row*LDW + 8 + col] = (_Float16)((float)sA[row*LDW + 8 + col] * rr);
                }
        __syncthreads();                       // sB (H*R) complete
        // ---- GEMM-H~ (reads sB) ----
        #pragma unroll
        for (int k = 0; k < 16; k++) g[k] = fz;
        gemm_pass(sB, B2t, 0, lr, lq, wc, g);
        __syncthreads();                       // all GEMM-H~ reads of sB done
        // epi-H~: ht -> sB.H (thread-owned slots; read back only by same thread in epi-Z)
        #pragma unroll
        for (int i = 0; i < 4; i++)
            #pragma unroll
            for (int j = 0; j < 4; j++)
                #pragma unroll
                for (int r = 0; r < 4; r++){
                    int row = i*16 + lq*4 + r;
                    int col = wc + j*16 + lr;
                    float val = g[i*4 + j][r] + bh_r[j];
                    float e2 = __expf(2.f*val);
                    sB[row*LDW + 8 + col] = (_Float16)(1.f - 2.f/(e2 + 1.f));
                }
        // ---- GEMM-Z (reads sA only) ----
        #pragma unroll
        for (int k = 0; k < 16; k++) g[k] = fz;
        gemm_pass(sA, B1t, 0, lr, lq, wc, g);
        __syncthreads();                       // all GEMM-Z reads of sA done
        // epi-Z: GRU update in place + attention accumulate (+ final relu fuse)
        #pragma unroll
        for (int i = 0; i < 4; i++)
            #pragma unroll
            for (int j = 0; j < 4; j++)
                #pragma unroll
                for (int r = 0; r < 4; r++){
                    int v = (i*4 + j)*4 + r;
                    int row = i*16 + lq*4 + r;
                    int col = wc + j*16 + lr;
                    float z  = 1.f / (1.f + __expf(-(g[i*4 + j][r] + bz_r[j])));
                    float h  = (float)sA[row*LDW + 8 + col];
                    float ht = (float)sB[row*LDW + 8 + col];
                    float hn = z*h + (1.f - z)*ht;
                    float a  = (float)acc[v>>1][v&1] + pt*hn;
                    acc[v>>1][v&1] = (_Float16)a;
                    sA[row*LDW + 8 + col] = (_Float16)(last ? fmaxf(a, 0.f) : hn);
                }
        if (!last){
            if (tid < 64)
                *(uint4*)(&sA[tid*LDW]) = *(const uint4*)(AXh + ((size_t)(t+1)*NPAD + n0 + tid)*8);
            else if (tid < 128)
                *(uint4*)(&sB[(tid-64)*LDW]) = *(const uint4*)(AXh + ((size_t)(t+1)*NPAD + n0 + (tid-64))*8);
        }
        __syncthreads();                       // H' (or relu(acc)), AXt+1 visible
    }

    // ---- MLP in place on sA; stale AXt cols nulled by zero rows in W*t ----
    const _Float16* Ws[3] = {W1t, W2t, W3t};
    const float*    bs[3] = {b1, b2, b3};
    for (int l = 0; l < 3; l++){
        #pragma unroll
        for (int k = 0; k < 16; k++) g[k] = fz;
        gemm_pass(sA, Ws[l], 0, lr, lq, wc, g);
        __syncthreads();                       // all reads done before in-place write
        #pragma unroll
        for (int i = 0; i < 4; i++)
            #pragma unroll
            for (int j = 0; j < 4; j++)
                #pragma unroll
                for (int r = 0; r < 4; r++){
                    int row = i*16 + lq*4 + r;
                    int col = wc + j*16 + lr;
                    sA[row*LDW + 8 + col] = (_Float16)fmaxf(g[i*4 + j][r] + bs[l][col], 0.f);
                }
        __syncthreads();
    }
    // ---- head: 64x18, wave 0 only ----
    if (wave == 0){
        #pragma unroll
        for (int k = 0; k < 16; k++) g[k] = fz;
        gemm_pass(sA, WoT, 0, lr, lq, 0, g);
        #pragma unroll
        for (int i = 0; i < 4; i++)
            #pragma unroll
            for (int j = 0; j < 4; j++)
                #pragma unroll
                for (int r = 0; r < 4; r++){
                    int row = i*16 + lq*4 + r;
                    int col = j*16 + lr;
                    int gm = n0 + row;
                    if (col < T_P && gm < N_NODES)
                        dout[(size_t)gm*T_P + col] = g[i*4 + j][r] + bo[col];
                }
    }
}

extern "C" void kernel_launch(void* const* d_in, const int* in_sizes, int n_in,
                              void* d_out, int out_size, void* d_ws, size_t ws_size,
                              hipStream_t stream){
    const float* x   = (const float*)d_in[0];
    const int*   ei  = (const int*)  d_in[1];
    const float* ew  = (const float*)d_in[2];
    const float* Wz  = (const float*)d_in[3];  const float* bz  = (const float*)d_in[4];
    const float* Wlz = (const float*)d_in[5];  const float* blz = (const float*)d_in[6];
    const float* Wr  = (const float*)d_in[7];  const float* br  = (const float*)d_in[8];
    const float* Wlr = (const float*)d_in[9];  const float* blr = (const float*)d_in[10];
    const float* Wh  = (const float*)d_in[11]; const float* bh  = (const float*)d_in[12];
    const float* Wlh = (const float*)d_in[13]; const float* blh = (const float*)d_in[14];
    const float* att = (const float*)d_in[15];
    const float* W1  = (const float*)d_in[16]; const float* b1  = (const float*)d_in[17];
    const float* W2  = (const float*)d_in[18]; const float* b2  = (const float*)d_in[19];
    const float* W3  = (const float*)d_in[20]; const float* b3  = (const float*)d_in[21];
    const float* Wo  = (const float*)d_in[22]; const float* bo  = (const float*)d_in[23];
    float* dout = (float*)d_out;

    char* ws = (char*)d_ws; size_t off = 0;
    auto alloc = [&](size_t bytes)->char*{ char* p = ws + off; off += (bytes + 255) & ~(size_t)255; return p; };
    _Float16* AXh   = (_Float16*)alloc((size_t)T_P*NPAD*8*2);   // 28.8M
    float*    deg   = (float*)alloc((size_t)N_NODES*4);
    float*    dinv  = (float*)alloc((size_t)N_NODES*4);
    int*      cnt   = (int*)  alloc((size_t)N_NODES*4);
    int*      rowp  = (int*)  alloc(((size_t)N_NODES + 1)*4);
    int*      ccur  = (int*)  alloc((size_t)N_NODES*4);
    int*      csrc  = (int*)  alloc((size_t)N_EDGES*4);
    float*    cnrm  = (float*)alloc((size_t)N_EDGES*4);
    int*      part  = (int*)  alloc((size_t)NB_SCAN*4);
    int*      pbase = (int*)  alloc((size_t)NB_SCAN*4);
    float*    wprime= (float*)alloc((size_t)3*8*U*4);
    float*    biasg = (float*)alloc((size_t)3*U*4);
    _Float16* B1t   = (_Float16*)alloc((size_t)512*KP*2);
    _Float16* B2t   = (_Float16*)alloc((size_t)256*KP*2);
    _Float16* W1t   = (_Float16*)alloc((size_t)U*KP*2);
    _Float16* W2t   = (_Float16*)alloc((size_t)U*KP*2);
    _Float16* W3t   = (_Float16*)alloc((size_t)U*KP*2);
    _Float16* WoT   = (_Float16*)alloc((size_t)64*KP*2);
    float*    probs = (float*)alloc((size_t)T_P*4);

    hipMemsetAsync(AXh, 0, (size_t)T_P*NPAD*8*2, stream);   // pad-node rows stay zero
    hipMemsetAsync(cnt, 0, (size_t)N_NODES*4, stream);

    k_probs<<<1, 64, 0, stream>>>(att, probs);
    k_wprime<<<(3*9*256 + 255)/256, 256, 0, stream>>>(Wz,bz,Wlz,blz, Wr,br,Wlr,blr, Wh,bh,Wlh,blh, wprime, biasg);
    k_fill_gates<<<(768*KP + 255)/256, 256, 0, stream>>>(wprime, Wlz, Wlr, Wlh, B1t, B2t);
    k_fill_mlp<<<(3*U*KP + 64*KP + 255)/256, 256, 0, stream>>>(W1, W2, W3, Wo, W1t, W2t, W3t, WoT);

    k_init_deg<<<(N_NODES + 255)/256, 256, 0, stream>>>(deg);
    k_deg<<<(N_EDGES + 255)/256, 256, 0, stream>>>(ei, ew, deg);
    k_dinv<<<(N_NODES + 255)/256, 256, 0, stream>>>(deg, dinv);
    k_count<<<(N_EDGES + 255)/256, 256, 0, stream>>>(ei, cnt);
    k_partial<<<NB_SCAN, 256, 0, stream>>>(cnt, part);
    k_scan_part<<<1, 512, 0, stream>>>(part, pbase);
    k_emit<<<NB_SCAN, 256, 0, stream>>>(cnt, pbase, rowp, ccur);
    k_scatter<<<(N_EDGES + 255)/256, 256, 0, stream>>>(ei, ew, dinv, ccur, csrc, cnrm);
    k_gather_nf<<<(N_NODES*8 + 255)/256, 256, 0, stream>>>(x, dinv, rowp, csrc, cnrm, AXh);

    k_fused<<<NPAD/64, 256, 0, stream>>>(AXh, B1t, B2t, biasg, W1t, W2t, W3t, WoT,
                                         b1, b2, b3, bo, probs, dout);
}

// Round 7
// 3130.530 us; speedup vs baseline: 1.4028x; 1.2592x over previous
//
#include <hip/hip_runtime.h>

typedef _Float16 h8 __attribute__((ext_vector_type(8)));
typedef _Float16 h2 __attribute__((ext_vector_type(2)));
typedef float f4 __attribute__((ext_vector_type(4)));

#define N_NODES 100000
#define NPAD    100096   // 1564*64
#define N_EDGES 1600000
#define T_P  18
#define U    256
#define KP   288         // padded K: 8 AXt + 256 H + 24 zero
#define LDW  296         // LDS row stride in halfs (148 words = 20 mod 32 -> 2-way alias only, free)
#define NB_SCAN 391      // ceil(N_NODES/256)

// ---------------- degree / norm / CSR ----------------
__global__ void k_init_deg(float* deg){
    int i = blockIdx.x*256 + threadIdx.x;
    if (i < N_NODES) deg[i] = 1.0f;
}
__global__ void k_deg(const int* __restrict__ ei, const float* __restrict__ w, float* deg){
    int e = blockIdx.x*256 + threadIdx.x;
    if (e < N_EDGES) atomicAdd(&deg[ei[N_EDGES + e]], w[e]);
}
__global__ void k_dinv(const float* deg, float* dinv){
    int i = blockIdx.x*256 + threadIdx.x;
    if (i < N_NODES) dinv[i] = rsqrtf(deg[i]);
}
__global__ void k_count(const int* __restrict__ ei, int* cnt){
    int e = blockIdx.x*256 + threadIdx.x;
    if (e < N_EDGES) atomicAdd(&cnt[ei[N_EDGES + e]], 1);
}
// parallel scan: per-256-chunk sums -> scan of partials -> emit offsets
__global__ void k_partial(const int* __restrict__ cnt, int* part){
    __shared__ int red[256];
    int b = blockIdx.x, i = b*256 + threadIdx.x;
    red[threadIdx.x] = (i < N_NODES) ? cnt[i] : 0;
    __syncthreads();
    for (int d = 128; d > 0; d >>= 1){
        if (threadIdx.x < d) red[threadIdx.x] += red[threadIdx.x + d];
        __syncthreads();
    }
    if (threadIdx.x == 0) part[b] = red[0];
}
__global__ void k_scan_part(const int* __restrict__ part, int* pbase){
    __shared__ int s[512];
    int tid = threadIdx.x;
    int v = (tid < NB_SCAN) ? part[tid] : 0;
    s[tid] = v; __syncthreads();
    for (int d = 1; d < 512; d <<= 1){
        int t2 = (tid >= d) ? s[tid - d] : 0;
        __syncthreads();
        s[tid] += t2;
        __syncthreads();
    }
    if (tid < NB_SCAN) pbase[tid] = s[tid] - v;   // exclusive
}
__global__ void k_emit(const int* __restrict__ cnt, const int* __restrict__ pbase,
                       int* rowp, int* ccur){
    __shared__ int s[256];
    int b = blockIdx.x, tid = threadIdx.x, i = b*256 + tid;
    int v = (i < N_NODES) ? cnt[i] : 0;
    s[tid] = v; __syncthreads();
    for (int d = 1; d < 256; d <<= 1){
        int t2 = (tid >= d) ? s[tid - d] : 0;
        __syncthreads();
        s[tid] += t2;
        __syncthreads();
    }
    int excl = s[tid] - v + pbase[b];
    if (i < N_NODES){
        rowp[i] = excl; ccur[i] = excl;
        if (i == N_NODES - 1) rowp[N_NODES] = excl + v;
    }
}
__global__ void k_scatter(const int* __restrict__ ei, const float* __restrict__ w,
                          const float* __restrict__ dinv, int* ccur,
                          int* __restrict__ csrc, float* __restrict__ cnrm){
    int e = blockIdx.x*256 + threadIdx.x;
    if (e >= N_EDGES) return;
    int s = ei[e], d = ei[N_EDGES + e];
    int pos = atomicAdd(&ccur[d], 1);
    csrc[pos] = s;
    cnrm[pos] = dinv[s] * w[e] * dinv[d];
}
// one thread per (node, feature): 18 time-accumulators, fp16 out
__global__ void k_gather_nf(const float* __restrict__ x, const float* __restrict__ dinv,
                            const int* __restrict__ rowp, const int* __restrict__ csrc,
                            const float* __restrict__ cnrm, _Float16* __restrict__ AXh){
    int idx = blockIdx.x*256 + threadIdx.x;
    if (idx >= N_NODES*8) return;
    int n = idx >> 3, f = idx & 7;
    float dv = dinv[n];
    float w0 = dv * dv;
    const float* xb = x + (size_t)n*144 + f*18;
    float s[T_P];
    #pragma unroll
    for (int t = 0; t < T_P; t++) s[t] = w0 * xb[t];
    int p1 = rowp[n+1];
    for (int p = rowp[n]; p < p1; p++){
        float w = cnrm[p];
        const float* xs = x + (size_t)csrc[p]*144 + f*18;
        #pragma unroll
        for (int t = 0; t < T_P; t++) s[t] += w * xs[t];
    }
    #pragma unroll
    for (int t = 0; t < T_P; t++)
        AXh[((size_t)t*NPAD + n)*8 + f] = (_Float16)s[t];
}

// ---------------- weight prep ----------------
__global__ void k_probs(const float* att, float* probs){
    if (threadIdx.x == 0 && blockIdx.x == 0){
        float mx = -1e30f;
        for (int t = 0; t < T_P; t++) mx = fmaxf(mx, att[t]);
        float e[T_P], s = 0.f;
        for (int t = 0; t < T_P; t++){ e[t] = __expf(att[t] - mx); s += e[t]; }
        for (int t = 0; t < T_P; t++) probs[t] = e[t] / s;
    }
}
__global__ void k_wprime(const float* Wz, const float* bz, const float* Wlz, const float* blz,
                         const float* Wr, const float* br, const float* Wlr, const float* blr,
                         const float* Wh, const float* bh, const float* Wlh, const float* blh,
                         float* wprime, float* biasg){
    int idx = blockIdx.x*256 + threadIdx.x;
    if (idx >= 3*9*256) return;
    int g = idx / (9*256); int rem = idx - g*9*256;
    int row = rem / 256;   int u = rem - row*256;
    const float* W  = g==0 ? Wz  : (g==1 ? Wr  : Wh);
    const float* Wl = g==0 ? Wlz : (g==1 ? Wlr : Wlh);
    const float* bb = g==0 ? bz  : (g==1 ? br  : bh);
    const float* bl = g==0 ? blz : (g==1 ? blr : blh);
    float s = 0.f;
    if (row < 8){
        for (int c = 0; c < U; c++) s += W[row*U + c] * Wl[c*U + u];
        wprime[(g*8 + row)*U + u] = s;
    } else {
        for (int c = 0; c < U; c++) s += bb[c] * Wl[c*U + u];
        biasg[g*U + u] = s + bl[u];
    }
}
// B1t [512][288] (Z|R), B2t [256][288] (H~), n-major fp16, K-padded with 0
__global__ void k_fill_gates(const float* __restrict__ wprime, const float* __restrict__ Wlz,
                             const float* __restrict__ Wlr, const float* __restrict__ Wlh,
                             _Float16* __restrict__ B1t, _Float16* __restrict__ B2t){
    int idx = blockIdx.x*256 + threadIdx.x;
    if (idx >= 768*KP) return;
    int n = idx / KP, k = idx - n*KP;
    int g = (n < 256) ? 0 : ((n < 512) ? 1 : 2);
    int u = n & 255;
    const float* Wl = g==0 ? Wlz : (g==1 ? Wlr : Wlh);
    float v;
    if (k < 8)        v = wprime[(g*8 + k)*U + u];
    else if (k < 264) v = Wl[(256 + (k - 8))*U + u];
    else              v = 0.f;
    if (n < 512) B1t[(size_t)n*KP + k] = (_Float16)v;
    else         B2t[(size_t)(n - 512)*KP + k] = (_Float16)v;
}
// MLP weights in same padded layout: rows k<8 and k>=264 are zero, k in [8,264) = W[k-8][n]
__global__ void k_fill_mlp(const float* __restrict__ W1, const float* __restrict__ W2,
                           const float* __restrict__ W3, const float* __restrict__ Wo,
                           _Float16* W1t, _Float16* W2t, _Float16* W3t, _Float16* WoT){
    int idx = blockIdx.x*256 + threadIdx.x;
    if (idx >= 3*U*KP + 64*KP) return;
    if (idx < 3*U*KP){
        int l = idx / (U*KP); int rem = idx - l*U*KP;
        int n = rem / KP, k = rem - n*KP;
        const float* W = l==0 ? W1 : (l==1 ? W2 : W3);
        _Float16*   Wt = l==0 ? W1t : (l==1 ? W2t : W3t);
        Wt[(size_t)n*KP + k] = (k >= 8 && k < 264) ? (_Float16)W[(size_t)(k-8)*U + n] : (_Float16)0.f;
    } else {
        int rem = idx - 3*U*KP;
        int n = rem / KP, k = rem - n*KP;
        WoT[(size_t)n*KP + k] = (n < T_P && k >= 8 && k < 264) ? (_Float16)Wo[(size_t)(k-8)*T_P + n] : (_Float16)0.f;
    }
}

// ---------------- fused recurrence + MLP ----------------
// wave tile = 64 rows x 32 cols: g[8] (4 row-frags x 2 col-frags)
__device__ __forceinline__ void gemm_pass(const _Float16* sbuf, const _Float16* __restrict__ Bg,
                                          int brow, int lr, int lq, f4* g){
    for (int kt = 0; kt < 9; kt++){
        h8 af[4], bf[2];
        #pragma unroll
        for (int i = 0; i < 4; i++)
            af[i] = *(const h8*)(sbuf + (i*16 + lr)*LDW + kt*32 + lq*8);
        #pragma unroll
        for (int j = 0; j < 2; j++)
            bf[j] = *(const h8*)(Bg + (size_t)(brow + j*16 + lr)*KP + kt*32 + lq*8);
        #pragma unroll
        for (int i = 0; i < 4; i++)
            #pragma unroll
            for (int j = 0; j < 2; j++)
                g[i*2 + j] = __builtin_amdgcn_mfma_f32_16x16x32_f16(af[i], bf[j], g[i*2 + j], 0, 0, 0);
    }
}

// Round-6 post-mortem: 64x64/wave tile needs ~190-320 unified regs -> either spills
// (128 cap) or 1 wave/SIMD (256). Fix: 512-thread blocks, 64x32/wave tile (~130 regs)
// + h/ht cached in regs -> 2 waves/SIMD at a safe 256-reg budget, zero spills.
__global__ __attribute__((amdgpu_waves_per_eu(2, 2))) __launch_bounds__(512)
void k_fused(const _Float16* __restrict__ AXh,
             const _Float16* __restrict__ B1t, const _Float16* __restrict__ B2t,
             const float* __restrict__ biasg,
             const _Float16* __restrict__ W1t, const _Float16* __restrict__ W2t,
             const _Float16* __restrict__ W3t, const _Float16* __restrict__ WoT,
             const float* __restrict__ b1, const float* __restrict__ b2,
             const float* __restrict__ b3, const float* __restrict__ bo,
             const float* __restrict__ probs, float* __restrict__ dout){
    __shared__ __align__(16) _Float16 sA[64*LDW];   // [AXt | H    | pad]
    __shared__ __align__(16) _Float16 sB[64*LDW];   // [AXt | H*R  | pad]
    const int tid  = threadIdx.x;
    const int wave = tid >> 6, lane = tid & 63;
    const int lr = lane & 15, lq = lane >> 4;
    const int wc = wave * 32;                        // this wave's 32 output cols
    const int n0 = blockIdx.x * 64;

    {   // zero both buffers (H cols start 0, pad cols stay 0)
        uint* w0 = (uint*)sA; uint* w1 = (uint*)sB;
        for (int i = tid; i < 64*LDW/2; i += 512){ w0[i] = 0u; w1[i] = 0u; }
    }
    __syncthreads();
    if (tid < 64)
        *(uint4*)(&sA[tid*LDW]) = *(const uint4*)(AXh + ((size_t)0*NPAD + n0 + tid)*8);
    else if (tid < 128)
        *(uint4*)(&sB[(tid-64)*LDW]) = *(const uint4*)(AXh + ((size_t)0*NPAD + n0 + (tid-64))*8);

    // hoist biases (constant across t): 6 VGPRs
    float bz_r[2], br_r[2], bh_r[2];
    #pragma unroll
    for (int j = 0; j < 2; j++){
        int col = wc + j*16 + lr;
        bz_r[j] = biasg[col];
        br_r[j] = biasg[256 + col];
        bh_r[j] = biasg[512 + col];
    }

    h2 acc[16], hr[16], htr[16];
    h2 z2 = {(_Float16)0.f, (_Float16)0.f};
    #pragma unroll
    for (int k = 0; k < 16; k++) acc[k] = z2;

    f4 g[8];
    const f4 fz = {0.f, 0.f, 0.f, 0.f};
    __syncthreads();

    for (int t = 0; t < T_P; t++){
        const float pt = probs[t];
        const int last = (t == T_P - 1);
        // ---- GEMM-R (reads sA) ----
        #pragma unroll
        for (int k = 0; k < 8; k++) g[k] = fz;
        gemm_pass(sA, B1t, 256 + wc, lr, lq, g);
        // epi-R: stash h in regs; sB.H = h * sigmoid(.)  (own slots)
        #pragma unroll
        for (int i = 0; i < 4; i++)
            #pragma unroll
            for (int j = 0; j < 2; j++)
                #pragma unroll
                for (int r = 0; r < 4; r++){
                    int v = (i*2 + j)*4 + r;
                    int row = i*16 + lq*4 + r;
                    int col = wc + j*16 + lr;
                    float rr = 1.f / (1.f + __expf(-(g[i*2 + j][r] + br_r[j])));
                    _Float16 h = sA[row*LDW + 8 + col];
                    hr[v>>1][v&1] = h;
                    sB[row*LDW + 8 + col] = (_Float16)((float)h * rr);
                }
        __syncthreads();                       // sB (H*R) complete
        // ---- GEMM-H~ (reads sB) ----
        #pragma unroll
        for (int k = 0; k < 8; k++) g[k] = fz;
        gemm_pass(sB, B2t, wc, lr, lq, g);
        // epi-H~: ht -> regs (no LDS)
        #pragma unroll
        for (int i = 0; i < 4; i++)
            #pragma unroll
            for (int j = 0; j < 2; j++)
                #pragma unroll
                for (int r = 0; r < 4; r++){
                    int v = (i*2 + j)*4 + r;
                    float val = g[i*2 + j][r] + bh_r[j];
                    float e2 = __expf(2.f*val);
                    htr[v>>1][v&1] = (_Float16)(1.f - 2.f/(e2 + 1.f));
                }
        // ---- GEMM-Z (reads sA only; no barrier needed since last one) ----
        #pragma unroll
        for (int k = 0; k < 8; k++) g[k] = fz;
        gemm_pass(sA, B1t, wc, lr, lq, g);
        __syncthreads();                       // all GEMM-Z/H~ reads done
        // epi-Z: GRU update in place + attention accumulate (+ final relu fuse)
        #pragma unroll
        for (int i = 0; i < 4; i++)
            #pragma unroll
            for (int j = 0; j < 2; j++)
                #pragma unroll
                for (int r = 0; r < 4; r++){
                    int v = (i*2 + j)*4 + r;
                    int row = i*16 + lq*4 + r;
                    int col = wc + j*16 + lr;
                    float z  = 1.f / (1.f + __expf(-(g[i*2 + j][r] + bz_r[j])));
                    float h  = (float)hr[v>>1][v&1];
                    float ht = (float)htr[v>>1][v&1];
                    float hn = z*h + (1.f - z)*ht;
                    float a  = (float)acc[v>>1][v&1] + pt*hn;
                    acc[v>>1][v&1] = (_Float16)a;
                    sA[row*LDW + 8 + col] = (_Float16)(last ? fmaxf(a, 0.f) : hn);
                }
        if (!last){
            if (tid < 64)
                *(uint4*)(&sA[tid*LDW]) = *(const uint4*)(AXh + ((size_t)(t+1)*NPAD + n0 + tid)*8);
            else if (tid < 128)
                *(uint4*)(&sB[(tid-64)*LDW]) = *(const uint4*)(AXh + ((size_t)(t+1)*NPAD + n0 + (tid-64))*8);
        }
        __syncthreads();                       // H' (or relu(acc)), AXt+1 visible
    }

    // ---- MLP in place on sA; stale AXt cols nulled by zero rows in W*t ----
    #pragma unroll
    for (int l = 0; l < 3; l++){
        const _Float16* Wt = (l == 0) ? W1t : (l == 1) ? W2t : W3t;
        const float*    bl = (l == 0) ? b1  : (l == 1) ? b2  : b3;
        #pragma unroll
        for (int k = 0; k < 8; k++) g[k] = fz;
        gemm_pass(sA, Wt, wc, lr, lq, g);
        __syncthreads();                       // all reads done before in-place write
        #pragma unroll
        for (int i = 0; i < 4; i++)
            #pragma unroll
            for (int j = 0; j < 2; j++)
                #pragma unroll
                for (int r = 0; r < 4; r++){
                    int row = i*16 + lq*4 + r;
                    int col = wc + j*16 + lr;
                    sA[row*LDW + 8 + col] = (_Float16)fmaxf(g[i*2 + j][r] + bl[col], 0.f);
                }
        __syncthreads();
    }
    // ---- head: 64x18, wave 0 only (wc==0 there) ----
    if (wave == 0){
        #pragma unroll
        for (int k = 0; k < 8; k++) g[k] = fz;
        gemm_pass(sA, WoT, 0, lr, lq, g);
        #pragma unroll
        for (int i = 0; i < 4; i++)
            #pragma unroll
            for (int j = 0; j < 2; j++)
                #pragma unroll
                for (int r = 0; r < 4; r++){
                    int row = i*16 + lq*4 + r;
                    int col = j*16 + lr;
                    int gm = n0 + row;
                    if (col < T_P && gm < N_NODES)
                        dout[(size_t)gm*T_P + col] = g[i*2 + j][r] + bo[col];
                }
    }
}

extern "C" void kernel_launch(void* const* d_in, const int* in_sizes, int n_in,
                              void* d_out, int out_size, void* d_ws, size_t ws_size,
                              hipStream_t stream){
    const float* x   = (const float*)d_in[0];
    const int*   ei  = (const int*)  d_in[1];
    const float* ew  = (const float*)d_in[2];
    const float* Wz  = (const float*)d_in[3];  const float* bz  = (const float*)d_in[4];
    const float* Wlz = (const float*)d_in[5];  const float* blz = (const float*)d_in[6];
    const float* Wr  = (const float*)d_in[7];  const float* br  = (const float*)d_in[8];
    const float* Wlr = (const float*)d_in[9];  const float* blr = (const float*)d_in[10];
    const float* Wh  = (const float*)d_in[11]; const float* bh  = (const float*)d_in[12];
    const float* Wlh = (const float*)d_in[13]; const float* blh = (const float*)d_in[14];
    const float* att = (const float*)d_in[15];
    const float* W1  = (const float*)d_in[16]; const float* b1  = (const float*)d_in[17];
    const float* W2  = (const float*)d_in[18]; const float* b2  = (const float*)d_in[19];
    const float* W3  = (const float*)d_in[20]; const float* b3  = (const float*)d_in[21];
    const float* Wo  = (const float*)d_in[22]; const float* bo  = (const float*)d_in[23];
    float* dout = (float*)d_out;

    char* ws = (char*)d_ws; size_t off = 0;
    auto alloc = [&](size_t bytes)->char*{ char* p = ws + off; off += (bytes + 255) & ~(size_t)255; return p; };
    _Float16* AXh   = (_Float16*)alloc((size_t)T_P*NPAD*8*2);   // 28.8M
    float*    deg   = (float*)alloc((size_t)N_NODES*4);
    float*    dinv  = (float*)alloc((size_t)N_NODES*4);
    int*      cnt   = (int*)  alloc((size_t)N_NODES*4);
    int*      rowp  = (int*)  alloc(((size_t)N_NODES + 1)*4);
    int*      ccur  = (int*)  alloc((size_t)N_NODES*4);
    int*      csrc  = (int*)  alloc((size_t)N_EDGES*4);
    float*    cnrm  = (float*)alloc((size_t)N_EDGES*4);
    int*      part  = (int*)  alloc((size_t)NB_SCAN*4);
    int*      pbase = (int*)  alloc((size_t)NB_SCAN*4);
    float*    wprime= (float*)alloc((size_t)3*8*U*4);
    float*    biasg = (float*)alloc((size_t)3*U*4);
    _Float16* B1t   = (_Float16*)alloc((size_t)512*KP*2);
    _Float16* B2t   = (_Float16*)alloc((size_t)256*KP*2);
    _Float16* W1t   = (_Float16*)alloc((size_t)U*KP*2);
    _Float16* W2t   = (_Float16*)alloc((size_t)U*KP*2);
    _Float16* W3t   = (_Float16*)alloc((size_t)U*KP*2);
    _Float16* WoT   = (_Float16*)alloc((size_t)64*KP*2);
    float*    probs = (float*)alloc((size_t)T_P*4);

    hipMemsetAsync(AXh, 0, (size_t)T_P*NPAD*8*2, stream);   // pad-node rows stay zero
    hipMemsetAsync(cnt, 0, (size_t)N_NODES*4, stream);

    k_probs<<<1, 64, 0, stream>>>(att, probs);
    k_wprime<<<(3*9*256 + 255)/256, 256, 0, stream>>>(Wz,bz,Wlz,blz, Wr,br,Wlr,blr, Wh,bh,Wlh,blh, wprime, biasg);
    k_fill_gates<<<(768*KP + 255)/256, 256, 0, stream>>>(wprime, Wlz, Wlr, Wlh, B1t, B2t);
    k_fill_mlp<<<(3*U*KP + 64*KP + 255)/256, 256, 0, stream>>>(W1, W2, W3, Wo, W1t, W2t, W3t, WoT);

    k_init_deg<<<(N_NODES + 255)/256, 256, 0, stream>>>(deg);
    k_deg<<<(N_EDGES + 255)/256, 256, 0, stream>>>(ei, ew, deg);
    k_dinv<<<(N_NODES + 255)/256, 256, 0, stream>>>(deg, dinv);
    k_count<<<(N_EDGES + 255)/256, 256, 0, stream>>>(ei, cnt);
    k_partial<<<NB_SCAN, 256, 0, stream>>>(cnt, part);
    k_scan_part<<<1, 512, 0, stream>>>(part, pbase);
    k_emit<<<NB_SCAN, 256, 0, stream>>>(cnt, pbase, rowp, ccur);
    k_scatter<<<(N_EDGES + 255)/256, 256, 0, stream>>>(ei, ew, dinv, ccur, csrc, cnrm);
    k_gather_nf<<<(N_NODES*8 + 255)/256, 256, 0, stream>>>(x, dinv, rowp, csrc, cnrm, AXh);

    k_fused<<<NPAD/64, 512, 0, stream>>>(AXh, B1t, B2t, biasg, W1t, W2t, W3t, WoT,
                                         b1, b2, b3, bo, probs, dout);
}